// Round 3
// baseline (6842.141 us; speedup 1.0000x reference)
//
#include <hip/hip_runtime.h>

namespace {

typedef __attribute__((ext_vector_type(8))) short bf16x8;
typedef __attribute__((ext_vector_type(4))) float f4;

constexpr int KST = 1024;
constexpr size_t OFF_R = (size_t)512 * KST * 5;
constexpr size_t OFF_D = OFF_R + (size_t)512 * KST * 8;

__device__ __forceinline__ float sigf(float x) { return 1.0f / (1.0f + __expf(-x)); }
__device__ __forceinline__ float tanhfast(float x) { float e2 = __expf(2.0f * x); return 1.0f - 2.0f / (e2 + 1.0f); }
__device__ __forceinline__ unsigned short bfr(float f) {
    unsigned u = __builtin_bit_cast(unsigned, f);
    return (unsigned short)((u + 0x7fffu + ((u >> 16) & 1u)) >> 16);
}
__device__ __forceinline__ float b2f(unsigned short h) {
    unsigned u = ((unsigned)h) << 16; return __builtin_bit_cast(float, u);
}
__device__ __forceinline__ f4 splat(float v) { f4 r = {v, v, v, v}; return r; }

#define MFMA(a, b, c) __builtin_amdgcn_mfma_f32_16x16x32_bf16((a), (b), (c), 0, 0, 0)

#define CHAIN_RHS(d, yy) { \
    float f1 = kf1 * yy[0] - kr1 * yy[1]; \
    float f2 = kf2 * yy[1] - kr2 * yy[2]; \
    float f3 = kf3 * yy[2] - kr3 * yy[3]; \
    float f4v = kf4 * yy[3] - kr4 * yy[4]; \
    d[0] = -f1; d[1] = f1 - f2; d[2] = f2 - f3; d[3] = f3 - f4v; d[4] = f4v; }

__global__ __launch_bounds__(512, 2) void rnn_mfma(
    const float* __restrict__ y0, const float* __restrict__ u_seq,
    const float* __restrict__ dt_seq, const float* __restrict__ W_lift,
    const float* __restrict__ b_lift, const float* __restrict__ W_ih,
    const float* __restrict__ W_hh, const float* __restrict__ b_ih,
    const float* __restrict__ b_hh, const float* __restrict__ W_head,
    const float* __restrict__ b_head, const float* __restrict__ u2y,
    float* __restrict__ out)
{
    const int t = threadIdx.x;
    const int lane = t & 63, wid = t >> 6;
    const int col = lane & 15, rg = lane >> 4;
    const int b0 = blockIdx.x * 16;

    // activation fragments, fragment-linear: lane l reads [kt][l][0..7] at byte l*16 (conflict-free)
    __shared__ alignas(16) short xAhi[2][64][8], xAlo[2][64][8];
    __shared__ alignas(16) short hAhi[4][64][8], hAlo[4][64][8];
    __shared__ alignas(16) short hWhi[4][64][8], hWlo[4][64][8];   // head W B-fragments
    __shared__ alignas(16) float sHfc[128][16];                    // h_prev f32, [q][row]
    __shared__ alignas(16) float sU[2][16][4];
    __shared__ float sDt[2][16];
    __shared__ alignas(16) float sRates[16][8];
    __shared__ alignas(16) float sDhid[16][8];
    __shared__ alignas(16) float sYf[16][8];
    __shared__ alignas(16) float sU2YT[5][4];

    // ---- per-wave weight B-fragments (registers, loaded once) ----
    // wave w owns N-tiles {w, w+8, w+16}: r-gate cols, z-gate cols, n-gate cols (same q range!)
    bf16x8 wihHi[3][2], wihLo[3][2], whhHi[3][4], whhLo[3][4];
    float bR, bZ, bIN, bHN;
    {
        const int rows[3] = { wid * 16 + col, 128 + wid * 16 + col, 256 + wid * 16 + col };
#pragma unroll
        for (int m = 0; m < 3; m++) {
            const int rr = rows[m];
#pragma unroll
            for (int kt = 0; kt < 2; kt++) {
                bf16x8 hi, lo;
#pragma unroll
                for (int jj = 0; jj < 8; jj++) {
                    float f = W_ih[(size_t)rr * 64 + kt * 32 + rg * 8 + jj];
                    unsigned short h = bfr(f);
                    hi[jj] = (short)h; lo[jj] = (short)bfr(f - b2f(h));
                }
                wihHi[m][kt] = hi; wihLo[m][kt] = lo;
            }
#pragma unroll
            for (int kt = 0; kt < 4; kt++) {
                bf16x8 hi, lo;
#pragma unroll
                for (int jj = 0; jj < 8; jj++) {
                    float f = W_hh[(size_t)rr * 128 + kt * 32 + rg * 8 + jj];
                    unsigned short h = bfr(f);
                    hi[jj] = (short)h; lo[jj] = (short)bfr(f - b2f(h));
                }
                whhHi[m][kt] = hi; whhLo[m][kt] = lo;
            }
        }
        bR = b_ih[rows[0]] + b_hh[rows[0]];
        bZ = b_ih[rows[1]] + b_hh[rows[1]];
        bIN = b_ih[rows[2]];
        bHN = b_hh[rows[2]];
    }
    const float bh = (col < 13) ? b_head[col] : 0.0f;

    // ---- lift weights: thread owns x-columns (c0, c0+1) for row lrow ----
    const int lrow = t & 15, lcp = t >> 4;
    const int c0 = lcp * 2;
    float wl[18], bl0, bl1;
#pragma unroll
    for (int j = 0; j < 9; j++) { wl[j] = W_lift[c0 * 9 + j]; wl[9 + j] = W_lift[(c0 + 1) * 9 + j]; }
    bl0 = b_lift[c0]; bl1 = b_lift[c0 + 1];

    // ---- LDS init ----
    for (int i = t; i < 1024; i += 512) { ((unsigned*)hAhi)[i] = 0u; ((unsigned*)hAlo)[i] = 0u; }
    for (int i = t; i < 2048; i += 512) ((float*)sHfc)[i] = 0.0f;
    if (t < 16) {
#pragma unroll
        for (int s = 0; s < 5; s++) sYf[t][s] = y0[(b0 + t) * 5 + s] + 0.01f;
    }
    if (t < 256) {
        int kt = t >> 6, l = t & 63, cc = l & 15, gg = l >> 4;
#pragma unroll
        for (int jj = 0; jj < 8; jj++) {
            int kk = kt * 32 + gg * 8 + jj;
            float f = (cc < 13) ? W_head[cc * 128 + kk] : 0.0f;
            unsigned short h = bfr(f);
            hWhi[kt][l][jj] = (short)h; hWlo[kt][l][jj] = (short)bfr(f - b2f(h));
        }
    }
    if (t < 20) { int s = t >> 2, j = t & 3; sU2YT[s][j] = u2y[j * 5 + s]; }
    if (t >= 64 && t < 128) { int l = t - 64, row = l >> 2, j = l & 3; sU[0][row][j] = u_seq[((size_t)(b0 + row) * KST) * 4 + j]; }
    if (t >= 128 && t < 144) { int r = t - 128; sDt[0][r] = dt_seq[(size_t)(b0 + r) * KST]; }

    float yv[5] = {0, 0, 0, 0, 0};
    if (t < 16) {
#pragma unroll
        for (int s = 0; s < 5; s++) yv[s] = y0[(b0 + t) * 5 + s] + 0.01f;
    }

    // accumulators enter each iteration holding bias + Whh·h_prev contribution (h_init = 0)
    f4 accR = splat(bR), accZ = splat(bZ), accIN = splat(bIN), accHN = splat(bHN);
    __syncthreads();

    for (int k = 0; k < KST; k++) {
        // ---------- A: lift -> x fragments ----------
        {
            f4 yq = *(const f4*)&sYf[lrow][0];
            float y4 = sYf[lrow][4];
            f4 uq = *(const f4*)&sU[k & 1][lrow][0];
            float a0 = bl0, a1 = bl1;
            a0 = fmaf(wl[0], uq[0], a0);  a1 = fmaf(wl[9],  uq[0], a1);
            a0 = fmaf(wl[1], uq[1], a0);  a1 = fmaf(wl[10], uq[1], a1);
            a0 = fmaf(wl[2], uq[2], a0);  a1 = fmaf(wl[11], uq[2], a1);
            a0 = fmaf(wl[3], uq[3], a0);  a1 = fmaf(wl[12], uq[3], a1);
            a0 = fmaf(wl[4], yq[0], a0);  a1 = fmaf(wl[13], yq[0], a1);
            a0 = fmaf(wl[5], yq[1], a0);  a1 = fmaf(wl[14], yq[1], a1);
            a0 = fmaf(wl[6], yq[2], a0);  a1 = fmaf(wl[15], yq[2], a1);
            a0 = fmaf(wl[7], yq[3], a0);  a1 = fmaf(wl[16], yq[3], a1);
            a0 = fmaf(wl[8], y4, a0);     a1 = fmaf(wl[17], y4, a1);
            float x0 = a0 * sigf(a0), x1 = a1 * sigf(a1);
            int kt = c0 >> 5, g = (c0 >> 3) & 3, e = c0 & 7, l2 = g * 16 + lrow;
            unsigned short h0 = bfr(x0), h1 = bfr(x1);
            *(unsigned*)&xAhi[kt][l2][e] = (unsigned)h0 | ((unsigned)h1 << 16);
            unsigned short g0 = bfr(x0 - b2f(h0)), g1 = bfr(x1 - b2f(h1));
            *(unsigned*)&xAlo[kt][l2][e] = (unsigned)g0 | ((unsigned)g1 << 16);
        }
        __syncthreads();

        // ---------- B: x-part MFMAs + gates (in-register) + h writeback ----------
        {
            bf16x8 xh0 = *(const bf16x8*)&xAhi[0][lane][0];
            bf16x8 xh1 = *(const bf16x8*)&xAhi[1][lane][0];
            bf16x8 xl0 = *(const bf16x8*)&xAlo[0][lane][0];
            bf16x8 xl1 = *(const bf16x8*)&xAlo[1][lane][0];
            accR = MFMA(xh0, wihHi[0][0], accR);  accR = MFMA(xh1, wihHi[0][1], accR);
            accR = MFMA(xl0, wihHi[0][0], accR);  accR = MFMA(xl1, wihHi[0][1], accR);
            accR = MFMA(xh0, wihLo[0][0], accR);  accR = MFMA(xh1, wihLo[0][1], accR);
            accZ = MFMA(xh0, wihHi[1][0], accZ);  accZ = MFMA(xh1, wihHi[1][1], accZ);
            accZ = MFMA(xl0, wihHi[1][0], accZ);  accZ = MFMA(xl1, wihHi[1][1], accZ);
            accZ = MFMA(xh0, wihLo[1][0], accZ);  accZ = MFMA(xh1, wihLo[1][1], accZ);
            accIN = MFMA(xh0, wihHi[2][0], accIN); accIN = MFMA(xh1, wihHi[2][1], accIN);
            accIN = MFMA(xl0, wihHi[2][0], accIN); accIN = MFMA(xl1, wihHi[2][1], accIN);
            accIN = MFMA(xh0, wihLo[2][0], accIN); accIN = MFMA(xh1, wihLo[2][1], accIN);

            const int q = wid * 16 + col;
            f4 hp = *(const f4*)&sHfc[q][rg * 4];
            float hn[4];
#pragma unroll
            for (int j = 0; j < 4; j++) {
                float rr = sigf(accR[j]);
                float zz = sigf(accZ[j]);
                float nn = tanhfast(fmaf(rr, accHN[j], accIN[j]));
                hn[j] = fmaf(zz, hp[j] - nn, nn);
            }
            f4 hnv = {hn[0], hn[1], hn[2], hn[3]};
            *(f4*)&sHfc[q][rg * 4] = hnv;
            const int kt = q >> 5, g = (q >> 3) & 3, e = q & 7;
#pragma unroll
            for (int j = 0; j < 4; j++) {
                int l2 = g * 16 + rg * 4 + j;
                unsigned short hh = bfr(hn[j]);
                hAhi[kt][l2][e] = (short)hh;
                hAlo[kt][l2][e] = (short)bfr(hn[j] - b2f(hh));
            }
            accR = splat(bR); accZ = splat(bZ); accIN = splat(bIN); accHN = splat(bHN);
        }
        __syncthreads();

        // ---------- D: head (wave 1) || h-part MFMAs for k+1 (other waves) ----------
        bf16x8 ah[4], al[4];
#pragma unroll
        for (int kt = 0; kt < 4; kt++) {
            ah[kt] = *(const bf16x8*)&hAhi[kt][lane][0];
            al[kt] = *(const bf16x8*)&hAlo[kt][lane][0];
        }
        if (wid == 1) {
            f4 accH = splat(bh);
#pragma unroll
            for (int kt = 0; kt < 4; kt++) {
                bf16x8 wh = *(const bf16x8*)&hWhi[kt][lane][0];
                bf16x8 wo = *(const bf16x8*)&hWlo[kt][lane][0];
                accH = MFMA(ah[kt], wh, accH);
                accH = MFMA(al[kt], wh, accH);
                accH = MFMA(ah[kt], wo, accH);
            }
#pragma unroll
            for (int j = 0; j < 4; j++) {
                int row = rg * 4 + j;
                float raw = accH[j];
                if (col < 8) {
                    float rate = fmaf(2.99f, sigf(raw), 0.01f);
                    sRates[row][col] = rate;
                    out[OFF_R + ((size_t)(b0 + row) * KST + k) * 8 + col] = rate;
                } else if (col < 13) {
                    float dh = 3.0f * sigf(raw);
                    sDhid[row][col - 8] = dh;
                    out[OFF_D + ((size_t)(b0 + row) * KST + k) * 5 + (col - 8)] = dh;
                }
            }
        } else {
#pragma unroll
            for (int kt = 0; kt < 4; kt++) {
                accR = MFMA(ah[kt], whhHi[0][kt], accR);
                accR = MFMA(al[kt], whhHi[0][kt], accR);
                accR = MFMA(ah[kt], whhLo[0][kt], accR);
                accZ = MFMA(ah[kt], whhHi[1][kt], accZ);
                accZ = MFMA(al[kt], whhHi[1][kt], accZ);
                accZ = MFMA(ah[kt], whhLo[1][kt], accZ);
                accHN = MFMA(ah[kt], whhHi[2][kt], accHN);
                accHN = MFMA(al[kt], whhHi[2][kt], accHN);
                accHN = MFMA(ah[kt], whhLo[2][kt], accHN);
            }
        }
        __syncthreads();

        // ---------- E: RK4 (wave 0) || wave 1 h-part MFMAs || prefetch ----------
        if (wid == 1) {
#pragma unroll
            for (int kt = 0; kt < 4; kt++) {
                accR = MFMA(ah[kt], whhHi[0][kt], accR);
                accR = MFMA(al[kt], whhHi[0][kt], accR);
                accR = MFMA(ah[kt], whhLo[0][kt], accR);
                accZ = MFMA(ah[kt], whhHi[1][kt], accZ);
                accZ = MFMA(al[kt], whhHi[1][kt], accZ);
                accZ = MFMA(ah[kt], whhLo[1][kt], accZ);
                accHN = MFMA(ah[kt], whhHi[2][kt], accHN);
                accHN = MFMA(al[kt], whhHi[2][kt], accHN);
                accHN = MFMA(ah[kt], whhLo[2][kt], accHN);
            }
        } else if (wid == 0) {
            if (lane < 16) {
                const int r = lane;
                f4 rv0 = *(const f4*)&sRates[r][0];
                f4 rv1 = *(const f4*)&sRates[r][4];
                float kf1 = rv0[0], kf2 = rv0[1], kf3 = rv0[2], kf4 = rv0[3];
                float kr1 = rv1[0], kr2 = rv1[1], kr3 = rv1[2], kr4 = rv1[3];
                f4 uq = *(const f4*)&sU[k & 1][r][0];
                float ya[5];
#pragma unroll
                for (int s = 0; s < 5; s++) {
                    f4 cw = *(const f4*)&sU2YT[s][0];
                    float jmp = uq[0] * cw[0];
                    jmp = fmaf(uq[1], cw[1], jmp);
                    jmp = fmaf(uq[2], cw[2], jmp);
                    jmp = fmaf(uq[3], cw[3], jmp);
                    ya[s] = yv[s] + jmp + sDhid[r][s];
                }
                const float hs = sDt[k & 1][r] * 0.1f;
                const float h2 = 0.5f * hs, h6 = hs * (1.0f / 6.0f);
                for (int ss = 0; ss < 10; ss++) {
                    float k1[5], k2[5], k3[5], k4[5], tp[5];
                    CHAIN_RHS(k1, ya);
#pragma unroll
                    for (int i = 0; i < 5; i++) tp[i] = fmaf(h2, k1[i], ya[i]);
                    CHAIN_RHS(k2, tp);
#pragma unroll
                    for (int i = 0; i < 5; i++) tp[i] = fmaf(h2, k2[i], ya[i]);
                    CHAIN_RHS(k3, tp);
#pragma unroll
                    for (int i = 0; i < 5; i++) tp[i] = fmaf(hs, k3[i], ya[i]);
                    CHAIN_RHS(k4, tp);
#pragma unroll
                    for (int i = 0; i < 5; i++) {
                        float sum = k1[i] + 2.0f * (k2[i] + k3[i]) + k4[i];
                        ya[i] = fmaxf(fmaf(h6, sum, ya[i]), 0.0f);
                    }
                }
#pragma unroll
                for (int s = 0; s < 5; s++) {
                    yv[s] = ya[s];
                    sYf[r][s] = ya[s];
                    out[((size_t)(b0 + r) * KST + k) * 5 + s] = ya[s];
                }
            }
        } else if (wid == 2) {
            if (k + 1 < KST) {
                int row = lane >> 2, j = lane & 3;
                sU[(k + 1) & 1][row][j] = u_seq[((size_t)(b0 + row) * KST + (k + 1)) * 4 + j];
            }
        } else if (wid == 3) {
            if (lane < 16 && k + 1 < KST)
                sDt[(k + 1) & 1][lane] = dt_seq[(size_t)(b0 + lane) * KST + (k + 1)];
        }
        __syncthreads();
    }
}

}  // namespace

extern "C" void kernel_launch(void* const* d_in, const int* in_sizes, int n_in,
                              void* d_out, int out_size, void* d_ws, size_t ws_size,
                              hipStream_t stream) {
    const float* y0     = (const float*)d_in[0];
    const float* u_seq  = (const float*)d_in[1];
    const float* dt_seq = (const float*)d_in[2];
    const float* W_lift = (const float*)d_in[3];
    const float* b_lift = (const float*)d_in[4];
    const float* W_ih   = (const float*)d_in[5];
    const float* W_hh   = (const float*)d_in[6];
    const float* b_ih   = (const float*)d_in[7];
    const float* b_hh   = (const float*)d_in[8];
    const float* W_head = (const float*)d_in[9];
    const float* b_head = (const float*)d_in[10];
    const float* u2y    = (const float*)d_in[11];
    float* out = (float*)d_out;

    rnn_mfma<<<32, 512, 0, stream>>>(y0, u_seq, dt_seq, W_lift, b_lift,
                                     W_ih, W_hh, b_ih, b_hh, W_head, b_head,
                                     u2y, out);
}